// Round 2
// baseline (263.161 us; speedup 1.0000x reference)
//
#include <hip/hip_runtime.h>

typedef __bf16 bf16x8 __attribute__((ext_vector_type(8)));
typedef __bf16 bf16x4 __attribute__((ext_vector_type(4)));
typedef float  floatx4 __attribute__((ext_vector_type(4)));

#define GLOBAL_AS __attribute__((address_space(1)))
#define LOCAL_AS  __attribute__((address_space(3)))

static constexpr int HID = 1024;
static constexpr int BM  = 256;   // samples per block
static constexpr int BN  = 256;   // featcols per block (n-slab)
static constexpr int BK  = 32;    // K per tile
static constexpr int NT  = HID / BK;  // 32 K-tiles

__device__ __forceinline__ void h8(bf16x8& d, float s0, float s1,
                                   const float4& w0a, const float4& w0b,
                                   const float4& w1a, const float4& w1b,
                                   const float4& ba,  const float4& bb) {
    d[0] = (__bf16)fmaxf(fmaf(s1, w1a.x, fmaf(s0, w0a.x, ba.x)), 0.f);
    d[1] = (__bf16)fmaxf(fmaf(s1, w1a.y, fmaf(s0, w0a.y, ba.y)), 0.f);
    d[2] = (__bf16)fmaxf(fmaf(s1, w1a.z, fmaf(s0, w0a.z, ba.z)), 0.f);
    d[3] = (__bf16)fmaxf(fmaf(s1, w1a.w, fmaf(s0, w0a.w, ba.w)), 0.f);
    d[4] = (__bf16)fmaxf(fmaf(s1, w1b.x, fmaf(s0, w0b.x, bb.x)), 0.f);
    d[5] = (__bf16)fmaxf(fmaf(s1, w1b.y, fmaf(s0, w0b.y, bb.y)), 0.f);
    d[6] = (__bf16)fmaxf(fmaf(s1, w1b.z, fmaf(s0, w0b.z, bb.z)), 0.f);
    d[7] = (__bf16)fmaxf(fmaf(s1, w1b.w, fmaf(s0, w0b.w, bb.w)), 0.f);
}

// ---------------------------------------------------------------------------
// prep: zero OUT + bake K-major-quad weight layouts for the 8-phase main.
//   W2T[((nt*32+kt)*4+q)*256+row][8] = bf16(W2[kt*32+q*8+j][nt*256+row])
//   WHT[(o*32+r)*8+j]               = bf16(W_heads[s][o*8+j][a]), r=s*4+a (<20)
// K-major sub-tiles make every ds_read_b128/global_load_lds quarter-wave hit
// 16 consecutive 16B slots -> bank-conflict-free with no XOR swizzle.
// ---------------------------------------------------------------------------
__global__ __launch_bounds__(256)
void prep_all(const float* __restrict__ W2, const float* __restrict__ WH,
              __bf16* __restrict__ W2T, __bf16* __restrict__ WHT,
              float* __restrict__ OUT) {
    int b = blockIdx.x;
    if (b < 256) {
        ((float4*)OUT)[(size_t)b * 256 + threadIdx.x]
            = make_float4(0.f, 0.f, 0.f, 0.f);
        return;
    }
    b -= 256;
    if (b < 256) {
        __shared__ __align__(16) __bf16 tile[64][72];  // 72: rows 16B-aligned
        const int bx = b & 15;   // n-tile
        const int by = b >> 4;   // k-tile
        const int a  = threadIdx.x & 63;
        const int bb = threadIdx.x >> 6;  // 0..3
#pragma unroll
        for (int r = 0; r < 16; ++r) {
            const int k = r * 4 + bb;
            tile[a][k] = (__bf16)W2[(size_t)(by * 64 + k) * HID + bx * 64 + a];
        }
        __syncthreads();
        const int n_loc = threadIdx.x & 63;
        const int w     = threadIdx.x >> 6;
        const int nt    = bx >> 2;
        const int row   = (bx & 3) * 64 + n_loc;
#pragma unroll
        for (int h = 0; h < 2; ++h) {
            const int ko   = w * 2 + h;          // k-octet in tile, 0..7
            const int kt   = by * 2 + (ko >> 2);
            const int quad = ko & 3;
            const bf16x8 v = *(const bf16x8*)&tile[n_loc][ko * 8];
            const size_t idx = ((size_t)(nt * NT + kt) * 4 + quad) * 256 + row;
            *(bf16x8*)(W2T + idx * 8) = v;
        }
    } else {
        const int r = b - 256;             // 0..31
        const int s = r >> 2, a = r & 3;
        for (int k = threadIdx.x; k < HID; k += 256) {
            const float v = (r < 20) ? WH[((size_t)s * HID + k) * 4 + a] : 0.f;
            WHT[(size_t)(k >> 3) * 256 + r * 8 + (k & 7)] = (__bf16)v;
        }
    }
}

// ---------------------------------------------------------------------------
// 256x256 8-wave counted-vmcnt schedule (T3+T4+T5) with fused layer-1.
//   A (=H) computed in-register -> ds_write, double-buffered, 1 tile ahead.
//   B (=W2T slab) global_load_lds, TRIPLE-buffered, staged 2 tiles ahead;
//   one s_waitcnt vmcnt(2) per tile (never drains to 0).
//   Phases: per tile, p0 = fm0-3 x fn0-3 (16 MFMA), p1 = fm4-7 x fn0-3.
//   LDS 128 KiB: A 2x16K + B 3x16K, featW [32][256][8] overlays for the head.
// ---------------------------------------------------------------------------
__global__ __launch_bounds__(512, 2)
void policy_main(const float* __restrict__ S,  const int* __restrict__ SK,
                 const float* __restrict__ W1, const float* __restrict__ B1,
                 const __bf16* __restrict__ W2T, const float* __restrict__ B2,
                 const __bf16* __restrict__ WHT, const float* __restrict__ BH,
                 float* __restrict__ OUT) {
    __shared__ __align__(16) char smem[131072];
    __bf16* A0    = (__bf16*)smem;             // [4][256][8] = 16 KiB
    __bf16* A1    = (__bf16*)(smem + 16384);
    __bf16* Bb    = (__bf16*)(smem + 32768);   // 3 x [4][256][8] = 48 KiB
    __bf16* featW = (__bf16*)smem;             // overlay [32][256][8] = 128 KiB

    const int tid  = threadIdx.x;
    const int lane = tid & 63;
    const int wv   = tid >> 6;       // 0..7
    const int l15  = lane & 15;
    const int quad = lane >> 4;
    const int wm   = wv >> 2;        // sample strip of 128
    const int wn   = wv & 3;         // featcol strip of 64
    const int n8   = blockIdx.x >> 8;     // 0..3 feature slab
    const int g    = blockIdx.x & 255;    // sample group
    const size_t i0 = (size_t)g * BM;

    const int octA = wv & 3;         // A-compute: K-octet (wave-uniform)
    const int sgrp = wv >> 2;        // A-compute: sample group bit

    floatx4 acc[8][4] = {};          // [fm sample-frag][fn featcol-frag]

    // ---- prologue: this lane's 2 sample states
    float2 sv[2];
    sv[0] = *(const float2*)(S + (i0 + sgrp * 64 + lane) * 2);
    sv[1] = *(const float2*)(S + (i0 + 128 + sgrp * 64 + lane) * 2);

    // ---- prologue: W1/B1 slab for tile 0 (before B stages -> older in vmcnt)
    float4 w0a = *(const float4*)(W1 + octA * 8);
    float4 w0b = *(const float4*)(W1 + octA * 8 + 4);
    float4 w1a = *(const float4*)(W1 + HID + octA * 8);
    float4 w1b = *(const float4*)(W1 + HID + octA * 8 + 4);
    float4 bba = *(const float4*)(B1 + octA * 8);
    float4 bbb = *(const float4*)(B1 + octA * 8 + 4);

    // ---- prologue: stage B[0], B[1] (2 loads each per wave)
#pragma unroll
    for (int t = 0; t < 2; ++t)
#pragma unroll
        for (int L = 0; L < 2; ++L) {
            const int c  = wv * 2 + L;       // chunk 0..15
            const int q  = c >> 2;
            const int r0 = (c & 3) * 64;
            const __bf16* gp = W2T
                + ((size_t)((n8 * NT + t) * 4 + q) * 256 + r0 + lane) * 8;
            __builtin_amdgcn_global_load_lds((GLOBAL_AS void*)gp,
                (LOCAL_AS void*)(Bb + t * 8192 + (q * 256 + r0) * 8), 16, 0, 0);
        }

    // ---- prologue: compute A[0] -> LDS
#pragma unroll
    for (int k = 0; k < 2; ++k) {
        const int smp = k * 128 + sgrp * 64 + lane;
        bf16x8 hv;
        h8(hv, sv[k].x, sv[k].y, w0a, w0b, w1a, w1b, bba, bbb);
        *(bf16x8*)(A0 + (octA * 256 + smp) * 8) = hv;
    }
    asm volatile("s_waitcnt vmcnt(2)" ::: "memory");   // B[0] done, B[1] in flight
    asm volatile("s_waitcnt lgkmcnt(0)" ::: "memory"); // A[0] writes done
    __builtin_amdgcn_s_barrier();

    int bcur = 0, bstg = 2;
#pragma unroll 1
    for (int t = 0; t < NT; ++t) {
        __bf16* Ac = (t & 1) ? A1 : A0;
        __bf16* An = (t & 1) ? A0 : A1;
        const __bf16* Bc = Bb + bcur * 8192;

        // ================= phase 0 =================
        bf16x8 wf[4], hf[4];
#pragma unroll
        for (int f = 0; f < 4; ++f)
            wf[f] = *(const bf16x8*)(Bc + (quad * 256 + wn * 64 + f * 16 + l15) * 8);
#pragma unroll
        for (int f = 0; f < 4; ++f)
            hf[f] = *(const bf16x8*)(Ac + (quad * 256 + wm * 128 + f * 16 + l15) * 8);
        // W1/B1 slab for tile t+1 (issued BEFORE stage -> use-wait keeps stage in flight)
        if (t < NT - 1) {
            const float* wp = W1 + (t + 1) * BK + octA * 8;
            w0a = *(const float4*)(wp);
            w0b = *(const float4*)(wp + 4);
            w1a = *(const float4*)(wp + HID);
            w1b = *(const float4*)(wp + HID + 4);
            bba = *(const float4*)(B1 + (t + 1) * BK + octA * 8);
            bbb = *(const float4*)(B1 + (t + 1) * BK + octA * 8 + 4);
        }
        // stage B[t+2] two tiles ahead
        if (t < NT - 2) {
#pragma unroll
            for (int L = 0; L < 2; ++L) {
                const int c  = wv * 2 + L;
                const int q  = c >> 2;
                const int r0 = (c & 3) * 64;
                const __bf16* gp = W2T
                    + ((size_t)((n8 * NT + (t + 2)) * 4 + q) * 256 + r0 + lane) * 8;
                __builtin_amdgcn_global_load_lds((GLOBAL_AS void*)gp,
                    (LOCAL_AS void*)(Bb + bstg * 8192 + (q * 256 + r0) * 8), 16, 0, 0);
            }
        }
        __builtin_amdgcn_s_barrier();
        asm volatile("s_waitcnt lgkmcnt(0)" ::: "memory");
        __builtin_amdgcn_s_setprio(1);
#pragma unroll
        for (int fm = 0; fm < 4; ++fm)
#pragma unroll
            for (int fn = 0; fn < 4; ++fn)
                acc[fm][fn] = __builtin_amdgcn_mfma_f32_16x16x32_bf16(
                    wf[fn], hf[fm], acc[fm][fn], 0, 0, 0);
        __builtin_amdgcn_s_setprio(0);
        __builtin_amdgcn_s_barrier();

        // ================= phase 1 =================
        bf16x8 hf2[4];
#pragma unroll
        for (int f = 0; f < 4; ++f)
            hf2[f] = *(const bf16x8*)(Ac + (quad * 256 + wm * 128 + 64 + f * 16 + l15) * 8);
        // compute A[t+1] -> other buffer (VALU rides the phase slot)
        if (t < NT - 1) {
#pragma unroll
            for (int k = 0; k < 2; ++k) {
                const int smp = k * 128 + sgrp * 64 + lane;
                bf16x8 hv;
                h8(hv, sv[k].x, sv[k].y, w0a, w0b, w1a, w1b, bba, bbb);
                *(bf16x8*)(An + (octA * 256 + smp) * 8) = hv;
            }
        }
        __builtin_amdgcn_s_barrier();
        asm volatile("s_waitcnt lgkmcnt(0)" ::: "memory");
        __builtin_amdgcn_s_setprio(1);
#pragma unroll
        for (int fm = 0; fm < 4; ++fm)
#pragma unroll
            for (int fn = 0; fn < 4; ++fn)
                acc[fm + 4][fn] = __builtin_amdgcn_mfma_f32_16x16x32_bf16(
                    wf[fn], hf2[fm], acc[fm + 4][fn], 0, 0, 0);
        __builtin_amdgcn_s_setprio(0);
        asm volatile("s_waitcnt vmcnt(2)" ::: "memory");  // B[t+1] done; B[t+2] stays in flight
        __builtin_amdgcn_s_barrier();

        bcur = (bcur == 2) ? 0 : bcur + 1;
        bstg = (bstg == 2) ? 0 : bstg + 1;
    }

    // ---- epilogue: relu(acc + b2) -> featW (K-major overlay)
#pragma unroll
    for (int fn = 0; fn < 4; ++fn) {
        const int fcb = wn * 64 + fn * 16 + quad * 4;
        const float4 b2v = *(const float4*)(B2 + n8 * 256 + fcb);
        const int o = fcb >> 3, j = fcb & 7;
#pragma unroll
        for (int fm = 0; fm < 8; ++fm) {
            const int smp = wm * 128 + fm * 16 + l15;
            const floatx4 v = acc[fm][fn];
            bf16x4 p;
            p[0] = (__bf16)fmaxf(v[0] + b2v.x, 0.f);
            p[1] = (__bf16)fmaxf(v[1] + b2v.y, 0.f);
            p[2] = (__bf16)fmaxf(v[2] + b2v.z, 0.f);
            p[3] = (__bf16)fmaxf(v[3] + b2v.w, 0.f);
            *(bf16x4*)(featW + (o * 256 + smp) * 8 + j) = p;
        }
    }
    __syncthreads();

    // ---- head MFMA: wave wv -> samples wv*32..+31; WHT read direct (L2-hot)
    floatx4 hacc[2][2] = {};
#pragma unroll
    for (int f2 = 0; f2 < 2; ++f2) {
        const int row = wv * 32 + f2 * 16 + l15;
#pragma unroll
        for (int ks2 = 0; ks2 < 8; ++ks2) {
            const bf16x8 fa = *(const bf16x8*)(featW
                                 + ((ks2 * 4 + quad) * 256 + row) * 8);
#pragma unroll
            for (int t2 = 0; t2 < 2; ++t2) {
                const int r  = t2 * 16 + l15;
                const int og = n8 * 32 + ks2 * 4 + quad;
                const bf16x8 wb = *(const bf16x8*)(WHT + ((size_t)og * 32 + r) * 8);
                hacc[f2][t2] = __builtin_amdgcn_mfma_f32_16x16x32_bf16(
                    fa, wb, hacc[f2][t2], 0, 0, 0);
            }
        }
    }

    // ---- atomic scatter: sample = quad*4+reg; emit selected skill's 4 actions
#pragma unroll
    for (int f2 = 0; f2 < 2; ++f2)
#pragma unroll
        for (int j = 0; j < 4; ++j) {
            const int smp = wv * 32 + f2 * 16 + quad * 4 + j;
            const int sk  = SK[i0 + smp];
#pragma unroll
            for (int t2 = 0; t2 < 2; ++t2) {
                const int hc = t2 * 16 + l15;
                const int d  = hc - sk * 4;
                if (d >= 0 && d < 4) {
                    float v = hacc[f2][t2][j];
                    if (n8 == 0) v += BH[hc];
                    atomicAdd(&OUT[(i0 + smp) * 4 + d], v);
                }
            }
        }
}

extern "C" void kernel_launch(void* const* d_in, const int* in_sizes, int n_in,
                              void* d_out, int out_size, void* d_ws, size_t ws_size,
                              hipStream_t stream) {
    const float* S  = (const float*)d_in[0];
    const int*   SK = (const int*)d_in[1];
    const float* W1 = (const float*)d_in[2];
    const float* B1 = (const float*)d_in[3];
    const float* W2 = (const float*)d_in[4];
    const float* B2 = (const float*)d_in[5];
    const float* WH = (const float*)d_in[6];
    const float* BH = (const float*)d_in[7];

    char* ws = (char*)d_ws;
    __bf16* W2T = (__bf16*)ws;                          // 2 MiB
    __bf16* WHT = (__bf16*)(ws + 2 * 1024 * 1024);      // 64 KiB

    hipLaunchKernelGGL(prep_all, dim3(544), dim3(256), 0, stream,
                       W2, WH, W2T, WHT, (float*)d_out);
    hipLaunchKernelGGL(policy_main, dim3(1024), dim3(512), 0, stream,
                       S, SK, W1, B1, W2T, B2, WHT, BH, (float*)d_out);
}

// Round 3
// 259.502 us; speedup vs baseline: 1.0141x; 1.0141x over previous
//
#include <hip/hip_runtime.h>

typedef __bf16 bf16x8 __attribute__((ext_vector_type(8)));
typedef __bf16 bf16x4 __attribute__((ext_vector_type(4)));
typedef float  floatx4 __attribute__((ext_vector_type(4)));

#define GLOBAL_AS __attribute__((address_space(1)))
#define LOCAL_AS  __attribute__((address_space(3)))

static constexpr int HID = 1024;
static constexpr int BK  = 32;        // K per tile
static constexpr int NT  = HID / BK;  // 32 K-tiles

__device__ __forceinline__ void h8(bf16x8& d, float s0, float s1,
                                   const float4& w0a, const float4& w0b,
                                   const float4& w1a, const float4& w1b,
                                   const float4& ba,  const float4& bb) {
    d[0] = (__bf16)fmaxf(fmaf(s1, w1a.x, fmaf(s0, w0a.x, ba.x)), 0.f);
    d[1] = (__bf16)fmaxf(fmaf(s1, w1a.y, fmaf(s0, w0a.y, ba.y)), 0.f);
    d[2] = (__bf16)fmaxf(fmaf(s1, w1a.z, fmaf(s0, w0a.z, ba.z)), 0.f);
    d[3] = (__bf16)fmaxf(fmaf(s1, w1a.w, fmaf(s0, w0a.w, ba.w)), 0.f);
    d[4] = (__bf16)fmaxf(fmaf(s1, w1b.x, fmaf(s0, w0b.x, bb.x)), 0.f);
    d[5] = (__bf16)fmaxf(fmaf(s1, w1b.y, fmaf(s0, w0b.y, bb.y)), 0.f);
    d[6] = (__bf16)fmaxf(fmaf(s1, w1b.z, fmaf(s0, w0b.z, bb.z)), 0.f);
    d[7] = (__bf16)fmaxf(fmaf(s1, w1b.w, fmaf(s0, w0b.w, bb.w)), 0.f);
}

// ---------------------------------------------------------------------------
// prep (unchanged layouts, r2-verified):
//   W2T[((nt*32+kt)*4+q)*256+row][8] = bf16(W2[kt*32+q*8+j][nt*256+row])
//   WHT[og*256 + r*8 + j]           = bf16(W_heads[s][og*8+j][a]), r=s*4+a (<20)
// ---------------------------------------------------------------------------
__global__ __launch_bounds__(256)
void prep_all(const float* __restrict__ W2, const float* __restrict__ WH,
              __bf16* __restrict__ W2T, __bf16* __restrict__ WHT,
              float* __restrict__ OUT) {
    int b = blockIdx.x;
    if (b < 256) {
        ((float4*)OUT)[(size_t)b * 256 + threadIdx.x]
            = make_float4(0.f, 0.f, 0.f, 0.f);
        return;
    }
    b -= 256;
    if (b < 256) {
        __shared__ __align__(16) __bf16 tile[64][72];
        const int bx = b & 15;   // n-tile
        const int by = b >> 4;   // k-tile
        const int a  = threadIdx.x & 63;
        const int bb = threadIdx.x >> 6;  // 0..3
#pragma unroll
        for (int r = 0; r < 16; ++r) {
            const int k = r * 4 + bb;
            tile[a][k] = (__bf16)W2[(size_t)(by * 64 + k) * HID + bx * 64 + a];
        }
        __syncthreads();
        const int n_loc = threadIdx.x & 63;
        const int w     = threadIdx.x >> 6;
        const int nt    = bx >> 2;
        const int row   = (bx & 3) * 64 + n_loc;
#pragma unroll
        for (int h = 0; h < 2; ++h) {
            const int ko   = w * 2 + h;          // k-octet in tile, 0..7
            const int kt   = by * 2 + (ko >> 2);
            const int quad = ko & 3;
            const bf16x8 v = *(const bf16x8*)&tile[n_loc][ko * 8];
            const size_t idx = ((size_t)(nt * NT + kt) * 4 + quad) * 256 + row;
            *(bf16x8*)(W2T + idx * 8) = v;
        }
    } else {
        const int r = b - 256;             // 0..31
        const int s = r >> 2, a = r & 3;
        for (int k = threadIdx.x; k < HID; k += 256) {
            const float v = (r < 20) ? WH[((size_t)s * HID + k) * 4 + a] : 0.f;
            WHT[(size_t)(k >> 3) * 256 + r * 8 + (k & 7)] = (__bf16)v;
        }
    }
}

// ---------------------------------------------------------------------------
// 256x256 counted-vmcnt schedule, 80 KiB LDS -> 2 blocks/CU (the r2 fix).
//   A (=H) in-register -> ds_write, dbuf; computed in phase 0 with W1 regs
//   loaded ONE TILE earlier (no VMEM latency inside the barrier-synced path).
//   B triple-buffered via global_load_lds staged 2 tiles ahead; end-of-tile
//   s_waitcnt vmcnt(8) (= 6 W1[t+2] + 2 B[t+2] younger), never drains.
//   Head: featW [16][256][8] = 64 KiB overlay, slab processed in 2 K=128
//   chunks so LDS stays at 80 KiB.
// ---------------------------------------------------------------------------
__global__ __launch_bounds__(512, 2)
void policy_main(const float* __restrict__ S,  const int* __restrict__ SK,
                 const float* __restrict__ W1, const float* __restrict__ B1,
                 const __bf16* __restrict__ W2T, const float* __restrict__ B2,
                 const __bf16* __restrict__ WHT, const float* __restrict__ BH,
                 float* __restrict__ OUT) {
    __shared__ __align__(16) char smem[81920];
    __bf16* A0    = (__bf16*)smem;             // [4][256][8] = 16 KiB
    __bf16* A1    = (__bf16*)(smem + 16384);
    __bf16* Bb    = (__bf16*)(smem + 32768);   // 3 x 16 KiB
    __bf16* featW = (__bf16*)smem;             // overlay [16][256][8] = 64 KiB

    const int tid  = threadIdx.x;
    const int lane = tid & 63;
    const int wv   = tid >> 6;       // 0..7
    const int l15  = lane & 15;
    const int quad = lane >> 4;
    const int wm   = wv >> 2;        // sample strip of 128
    const int wn   = wv & 3;         // featcol strip of 64
    const int n8   = blockIdx.x >> 8;     // 0..3 feature slab
    const int g    = blockIdx.x & 255;    // sample group
    const size_t i0 = (size_t)g * 256;

    const int octA = wv & 3;         // A-compute: K-octet (wave-uniform)
    const int sgrp = wv >> 2;        // A-compute: sample group bit

    floatx4 acc[8][4] = {};          // [fm sample-frag][fn featcol-frag]

    // ---- prologue: this lane's 2 sample states
    const float2 sv0 = *(const float2*)(S + (i0 + sgrp * 64 + lane) * 2);
    const float2 sv1 = *(const float2*)(S + (i0 + 128 + sgrp * 64 + lane) * 2);

    // ---- prologue: W1/B1 slab for tile 0
    float4 w0a, w0b, w1a, w1b, bba, bbb;
    {
        const float* wp = W1 + octA * 8;
        w0a = *(const float4*)(wp);
        w0b = *(const float4*)(wp + 4);
        w1a = *(const float4*)(wp + HID);
        w1b = *(const float4*)(wp + HID + 4);
        bba = *(const float4*)(B1 + octA * 8);
        bbb = *(const float4*)(B1 + octA * 8 + 4);
    }

    // ---- prologue: stage B[0], B[1]
#pragma unroll
    for (int t = 0; t < 2; ++t)
#pragma unroll
        for (int L = 0; L < 2; ++L) {
            const int c  = wv * 2 + L;       // chunk 0..15
            const int q  = c >> 2;
            const int r0 = (c & 3) * 64;
            const __bf16* gp = W2T
                + ((size_t)((n8 * NT + t) * 4 + q) * 256 + r0 + lane) * 8;
            __builtin_amdgcn_global_load_lds((GLOBAL_AS void*)gp,
                (LOCAL_AS void*)(Bb + t * 8192 + (q * 256 + r0) * 8), 16, 0, 0);
        }

    // ---- prologue: compute A[0] -> A0 (uses W1[0] regs)
    {
        bf16x8 hv;
        h8(hv, sv0.x, sv0.y, w0a, w0b, w1a, w1b, bba, bbb);
        *(bf16x8*)(A0 + (octA * 256 + sgrp * 64 + lane) * 8) = hv;
        h8(hv, sv1.x, sv1.y, w0a, w0b, w1a, w1b, bba, bbb);
        *(bf16x8*)(A0 + (octA * 256 + 128 + sgrp * 64 + lane) * 8) = hv;
    }

    // ---- prologue: reload W1 set <- W1[1] (consumed at tile 0)
    {
        const float* wp = W1 + BK + octA * 8;
        w0a = *(const float4*)(wp);
        w0b = *(const float4*)(wp + 4);
        w1a = *(const float4*)(wp + HID);
        w1b = *(const float4*)(wp + HID + 4);
        bba = *(const float4*)(B1 + BK + octA * 8);
        bbb = *(const float4*)(B1 + BK + octA * 8 + 4);
    }

    // B[0] arrived (younger: 2x B[1] stage + 6x W1[1]); A0 writes drained
    asm volatile("s_waitcnt vmcnt(8) lgkmcnt(0)" ::: "memory");
    __builtin_amdgcn_s_barrier();

    int bcur = 0, bstg = 2;
#pragma unroll 1
    for (int t = 0; t < NT; ++t) {
        __bf16* Ac = (t & 1) ? A1 : A0;
        __bf16* An = (t & 1) ? A0 : A1;
        const __bf16* Bc = Bb + bcur * 8192;

        // ================= phase 0: reads + A[t+1] + prefetch =================
        bf16x8 wf[4], hf[4];
#pragma unroll
        for (int f = 0; f < 4; ++f)
            wf[f] = *(const bf16x8*)(Bc + (quad * 256 + wn * 64 + f * 16 + l15) * 8);
#pragma unroll
        for (int f = 0; f < 4; ++f)
            hf[f] = *(const bf16x8*)(Ac + (quad * 256 + wm * 128 + f * 16 + l15) * 8);
        // A[t+1] from W1 regs loaded at tile t-1 (use-wait = vmcnt(2): B[t+1]
        // stays in flight; latency already hidden by 2 full phases)
        if (t < NT - 1) {
            bf16x8 hv;
            h8(hv, sv0.x, sv0.y, w0a, w0b, w1a, w1b, bba, bbb);
            *(bf16x8*)(An + (octA * 256 + sgrp * 64 + lane) * 8) = hv;
            h8(hv, sv1.x, sv1.y, w0a, w0b, w1a, w1b, bba, bbb);
            *(bf16x8*)(An + (octA * 256 + 128 + sgrp * 64 + lane) * 8) = hv;
        }
        // reload W1 set <- W1[t+2] (consumed at tile t+1)
        if (t < NT - 2) {
            const float* wp = W1 + (t + 2) * BK + octA * 8;
            w0a = *(const float4*)(wp);
            w0b = *(const float4*)(wp + 4);
            w1a = *(const float4*)(wp + HID);
            w1b = *(const float4*)(wp + HID + 4);
            bba = *(const float4*)(B1 + (t + 2) * BK + octA * 8);
            bbb = *(const float4*)(B1 + (t + 2) * BK + octA * 8 + 4);
        }
        // stage B[t+2] two tiles ahead
        if (t < NT - 2) {
#pragma unroll
            for (int L = 0; L < 2; ++L) {
                const int c  = wv * 2 + L;
                const int q  = c >> 2;
                const int r0 = (c & 3) * 64;
                const __bf16* gp = W2T
                    + ((size_t)((n8 * NT + (t + 2)) * 4 + q) * 256 + r0 + lane) * 8;
                __builtin_amdgcn_global_load_lds((GLOBAL_AS void*)gp,
                    (LOCAL_AS void*)(Bb + bstg * 8192 + (q * 256 + r0) * 8), 16, 0, 0);
            }
        }
        __builtin_amdgcn_s_barrier();
        asm volatile("s_waitcnt lgkmcnt(0)" ::: "memory");
        __builtin_amdgcn_s_setprio(1);
#pragma unroll
        for (int fm = 0; fm < 4; ++fm)
#pragma unroll
            for (int fn = 0; fn < 4; ++fn)
                acc[fm][fn] = __builtin_amdgcn_mfma_f32_16x16x32_bf16(
                    wf[fn], hf[fm], acc[fm][fn], 0, 0, 0);
        __builtin_amdgcn_s_setprio(0);
        __builtin_amdgcn_s_barrier();

        // ================= phase 1: pure read + MFMA =================
        bf16x8 hf2[4];
#pragma unroll
        for (int f = 0; f < 4; ++f)
            hf2[f] = *(const bf16x8*)(Ac + (quad * 256 + wm * 128 + 64 + f * 16 + l15) * 8);
        __builtin_amdgcn_s_barrier();
        asm volatile("s_waitcnt lgkmcnt(0)" ::: "memory");
        __builtin_amdgcn_s_setprio(1);
#pragma unroll
        for (int fm = 0; fm < 4; ++fm)
#pragma unroll
            for (int fn = 0; fn < 4; ++fn)
                acc[fm + 4][fn] = __builtin_amdgcn_mfma_f32_16x16x32_bf16(
                    wf[fn], hf2[fm], acc[fm + 4][fn], 0, 0, 0);
        __builtin_amdgcn_s_setprio(0);
        // B[t+1] arrived: younger = 6x W1[t+2] + 2x B[t+2] when staged
        if (t < NT - 2)
            asm volatile("s_waitcnt vmcnt(8)" ::: "memory");
        else
            asm volatile("s_waitcnt vmcnt(0)" ::: "memory");
        __builtin_amdgcn_s_barrier();

        bcur = (bcur == 2) ? 0 : bcur + 1;
        bstg = (bstg == 2) ? 0 : bstg + 1;
    }

    // ---- head epilogue: slab in 2 K=128 chunks through 64 KiB featW overlay
    floatx4 hacc[2][2] = {};
#pragma unroll
    for (int c = 0; c < 2; ++c) {
        if ((wn >> 1) == c) {
#pragma unroll
            for (int fn = 0; fn < 4; ++fn) {
                const int fcb = (wn & 1) * 64 + fn * 16 + quad * 4;  // 0..127
                const float4 b2v = *(const float4*)(B2 + n8 * 256 + c * 128 + fcb);
                const int o = fcb >> 3, j = fcb & 7;
#pragma unroll
                for (int fm = 0; fm < 8; ++fm) {
                    const int smp = wm * 128 + fm * 16 + l15;
                    const floatx4 v = acc[fm][fn];
                    bf16x4 p;
                    p[0] = (__bf16)fmaxf(v[0] + b2v.x, 0.f);
                    p[1] = (__bf16)fmaxf(v[1] + b2v.y, 0.f);
                    p[2] = (__bf16)fmaxf(v[2] + b2v.z, 0.f);
                    p[3] = (__bf16)fmaxf(v[3] + b2v.w, 0.f);
                    *(bf16x4*)(featW + (o * 256 + smp) * 8 + j) = p;
                }
            }
        }
        __syncthreads();
#pragma unroll
        for (int f2 = 0; f2 < 2; ++f2) {
            const int row = wv * 32 + f2 * 16 + l15;
#pragma unroll
            for (int ks2 = 0; ks2 < 4; ++ks2) {
                const bf16x8 fa = *(const bf16x8*)(featW
                                     + ((ks2 * 4 + quad) * 256 + row) * 8);
#pragma unroll
                for (int t2 = 0; t2 < 2; ++t2) {
                    const int r  = t2 * 16 + l15;
                    const int og = n8 * 32 + c * 16 + ks2 * 4 + quad;
                    const bf16x8 wb = *(const bf16x8*)(WHT + (size_t)og * 256 + r * 8);
                    hacc[f2][t2] = __builtin_amdgcn_mfma_f32_16x16x32_bf16(
                        fa, wb, hacc[f2][t2], 0, 0, 0);
                }
            }
        }
        __syncthreads();
    }

    // ---- atomic scatter: sample = quad*4+reg; emit selected skill's 4 actions
#pragma unroll
    for (int f2 = 0; f2 < 2; ++f2)
#pragma unroll
        for (int j = 0; j < 4; ++j) {
            const int smp = wv * 32 + f2 * 16 + quad * 4 + j;
            const int sk  = SK[i0 + smp];
#pragma unroll
            for (int t2 = 0; t2 < 2; ++t2) {
                const int hc = t2 * 16 + l15;
                const int d  = hc - sk * 4;
                if (d >= 0 && d < 4) {
                    float v = hacc[f2][t2][j];
                    if (n8 == 0) v += BH[hc];
                    atomicAdd(&OUT[(i0 + smp) * 4 + d], v);
                }
            }
        }
}

extern "C" void kernel_launch(void* const* d_in, const int* in_sizes, int n_in,
                              void* d_out, int out_size, void* d_ws, size_t ws_size,
                              hipStream_t stream) {
    const float* S  = (const float*)d_in[0];
    const int*   SK = (const int*)d_in[1];
    const float* W1 = (const float*)d_in[2];
    const float* B1 = (const float*)d_in[3];
    const float* W2 = (const float*)d_in[4];
    const float* B2 = (const float*)d_in[5];
    const float* WH = (const float*)d_in[6];
    const float* BH = (const float*)d_in[7];

    char* ws = (char*)d_ws;
    __bf16* W2T = (__bf16*)ws;                          // 2 MiB
    __bf16* WHT = (__bf16*)(ws + 2 * 1024 * 1024);      // 64 KiB

    hipLaunchKernelGGL(prep_all, dim3(544), dim3(256), 0, stream,
                       W2, WH, W2T, WHT, (float*)d_out);
    hipLaunchKernelGGL(policy_main, dim3(1024), dim3(512), 0, stream,
                       S, SK, W1, B1, W2T, B2, WHT, BH, (float*)d_out);
}

// Round 4
// 224.782 us; speedup vs baseline: 1.1707x; 1.1545x over previous
//
#include <hip/hip_runtime.h>

typedef __bf16 bf16x8 __attribute__((ext_vector_type(8)));
typedef __bf16 bf16x4 __attribute__((ext_vector_type(4)));
typedef float  floatx4 __attribute__((ext_vector_type(4)));

#define GLOBAL_AS __attribute__((address_space(1)))
#define LOCAL_AS  __attribute__((address_space(3)))

static constexpr int HID = 1024;
static constexpr int BK  = 64;        // K per tile
static constexpr int KIT = HID / BK;  // 16 K-tiles

__device__ __forceinline__ void h8(bf16x8& d, float s0, float s1,
                                   const float4& w0a, const float4& w0b,
                                   const float4& w1a, const float4& w1b,
                                   const float4& ba,  const float4& bb) {
    d[0] = (__bf16)fmaxf(fmaf(s1, w1a.x, fmaf(s0, w0a.x, ba.x)), 0.f);
    d[1] = (__bf16)fmaxf(fmaf(s1, w1a.y, fmaf(s0, w0a.y, ba.y)), 0.f);
    d[2] = (__bf16)fmaxf(fmaf(s1, w1a.z, fmaf(s0, w0a.z, ba.z)), 0.f);
    d[3] = (__bf16)fmaxf(fmaf(s1, w1a.w, fmaf(s0, w0a.w, ba.w)), 0.f);
    d[4] = (__bf16)fmaxf(fmaf(s1, w1b.x, fmaf(s0, w0b.x, bb.x)), 0.f);
    d[5] = (__bf16)fmaxf(fmaf(s1, w1b.y, fmaf(s0, w0b.y, bb.y)), 0.f);
    d[6] = (__bf16)fmaxf(fmaf(s1, w1b.z, fmaf(s0, w0b.z, bb.z)), 0.f);
    d[7] = (__bf16)fmaxf(fmaf(s1, w1b.w, fmaf(s0, w0b.w, bb.w)), 0.f);
}

// ---------------------------------------------------------------------------
// prep:
//   [0,256)    zero OUT
//   [256,512)  W2 [K][N] fp32 -> W2T K-octet-major bf16:
//              W2T[(((slab*16+kt)*8+oct)*256+col)*8 + j]
//                = W2[kt*64+oct*8+j][slab*256+col]
//   [512,544)  W_heads -> WHT[(k>>3)*256 + r*8 + (k&7)], r=s*4+a (<20), else 0
// K-octet-major layout: every quarter-wave of a ds_read_b128 /
// global_load_lds touches 16 consecutive 16B slots -> conflict-free, no XOR.
// ---------------------------------------------------------------------------
__global__ __launch_bounds__(256)
void prep_all(const float* __restrict__ W2, const float* __restrict__ WH,
              __bf16* __restrict__ W2T, __bf16* __restrict__ WHT,
              float* __restrict__ OUT) {
    int b = blockIdx.x;
    if (b < 256) {
        ((float4*)OUT)[(size_t)b * 256 + threadIdx.x]
            = make_float4(0.f, 0.f, 0.f, 0.f);
        return;
    }
    b -= 256;
    if (b < 256) {
        __shared__ __align__(16) __bf16 tile[64][72];  // [col][k], rows 16B-aligned
        const int bx = b & 15;   // 64-col group
        const int by = b >> 4;   // 64-k group (= kt)
        const int a  = threadIdx.x & 63;
        const int bb = threadIdx.x >> 6;  // 0..3
#pragma unroll
        for (int r = 0; r < 16; ++r) {
            const int k = r * 4 + bb;
            tile[a][k] = (__bf16)W2[(size_t)(by * 64 + k) * HID + bx * 64 + a];
        }
        __syncthreads();
        const int slab = bx >> 2;
#pragma unroll
        for (int p = 0; p < 2; ++p) {
            const int idx = p * 256 + threadIdx.x;   // 0..511
            const int c   = idx & 63;
            const int oct = idx >> 6;                // 0..7
            const bf16x8 v = *(const bf16x8*)&tile[c][oct * 8];
            const int col = (bx & 3) * 64 + c;
            const size_t dst = ((size_t)(slab * KIT + by) * 8 + oct) * 256 + col;
            *(bf16x8*)(W2T + dst * 8) = v;
        }
    } else {
        const int r = b - 256;             // 0..31
        const int s = r >> 2, a = r & 3;
        for (int k = threadIdx.x; k < HID; k += 256) {
            const float v = (r < 20) ? WH[((size_t)s * HID + k) * 4 + a] : 0.f;
            WHT[(size_t)(k >> 3) * 256 + r * 8 + (k & 7)] = (__bf16)v;
        }
    }
}

// ---------------------------------------------------------------------------
// Round-1 PROVEN structure (4 waves, simple 2-barrier K-loop, 40960 B LDS,
// ~3 blocks/CU) with the tile reshaped 128x128 -> 64x256:
//   - layer-1 h8 work per thread per tile HALVES (slab redundancy 8 -> 4)
//   - atomics + SK reads halve; B L2 traffic doubles (absorbable)
//   - per-wave output stays 64x64 (acc[4][4], 64 AGPR) -> same occupancy class
//   - all LDS in K-octet-major [oct][row][8]: conflict-free reads AND writes
// Head: featL [32 oct][64 smp][8] = 32 KiB overlays Bt; WHT direct from L2.
// ---------------------------------------------------------------------------
__global__ __launch_bounds__(256, 3)
void policy_main(const float* __restrict__ S,  const int* __restrict__ SK,
                 const float* __restrict__ W1, const float* __restrict__ B1,
                 const __bf16* __restrict__ W2T, const float* __restrict__ B2,
                 const __bf16* __restrict__ WHT, const float* __restrict__ BH,
                 float* __restrict__ OUT) {
    __shared__ __align__(16) char smem[40960];
    __bf16* At    = (__bf16*)smem;            // [8 oct][64 smp][8]  = 8 KiB
    __bf16* Bt    = (__bf16*)(smem + 8192);   // [8 oct][256 col][8] = 32 KiB
    __bf16* featL = (__bf16*)(smem + 8192);   // overlay [32 oct][64 smp][8]

    const int tid  = threadIdx.x;
    const int lane = tid & 63;
    const int wv   = tid >> 6;       // 0..3  (featcol strip of 64)
    const int l15  = lane & 15;
    const int quad = lane >> 4;
    const int slab = blockIdx.x >> 10;      // 0..3 (256-col slab; co-resident
    const int g    = blockIdx.x & 1023;     //       blocks share a slab -> L2)
    const size_t i0 = (size_t)g * 64;

    const int octA = wv * 2 + (lane >> 5);  // A-compute k-octet
    const int smpA = lane & 31;             // A-compute sample

    floatx4 acc[4][4] = {};   // [fn featcol-frag][fm sample-frag]

    // ---- prologue: this lane's 2 sample states
    const float2 sv0 = *(const float2*)(S + (i0 + smpA) * 2);
    const float2 sv1 = *(const float2*)(S + (i0 + 32 + smpA) * 2);

#pragma unroll 1
    for (int kt = 0; kt < KIT; ++kt) {
        __syncthreads();   // previous tile's frag readers done
        // ---- stage B: 8 chunks/wave; wave -> col strip wv*64, chunk L -> oct
#pragma unroll
        for (int L = 0; L < 8; ++L) {
            const __bf16* gp = W2T
                + (((size_t)(slab * KIT + kt) * 8 + L) * 256 + wv * 64 + lane) * 8;
            __builtin_amdgcn_global_load_lds((GLOBAL_AS void*)gp,
                (LOCAL_AS void*)(Bt + (L * 256 + wv * 64) * 8), 16, 0, 0);
        }
        // ---- compute A tile (H): lane -> octet octA, samples smpA, smpA+32
        {
            const float* wp = W1 + kt * BK + octA * 8;
            const float4 w0a = *(const float4*)(wp);
            const float4 w0b = *(const float4*)(wp + 4);
            const float4 w1a = *(const float4*)(wp + HID);
            const float4 w1b = *(const float4*)(wp + HID + 4);
            const float4 ba  = *(const float4*)(B1 + kt * BK + octA * 8);
            const float4 bb  = *(const float4*)(B1 + kt * BK + octA * 8 + 4);
            bf16x8 hv;
            h8(hv, sv0.x, sv0.y, w0a, w0b, w1a, w1b, ba, bb);
            *(bf16x8*)(At + (octA * 64 + smpA) * 8) = hv;
            h8(hv, sv1.x, sv1.y, w0a, w0b, w1a, w1b, ba, bb);
            *(bf16x8*)(At + (octA * 64 + 32 + smpA) * 8) = hv;
        }
        __syncthreads();   // drain staging + A writes (compiler emits full drain)
        // ---- 2 k-steps of 32: 8 frag reads + 16 MFMA each
#pragma unroll
        for (int ks = 0; ks < 2; ++ks) {
            bf16x8 wf[4], hf[4];
#pragma unroll
            for (int f = 0; f < 4; ++f)
                wf[f] = *(const bf16x8*)(Bt
                         + (((ks * 4 + quad) * 256) + wv * 64 + f * 16 + l15) * 8);
#pragma unroll
            for (int f = 0; f < 4; ++f)
                hf[f] = *(const bf16x8*)(At
                         + (((ks * 4 + quad) * 64) + f * 16 + l15) * 8);
#pragma unroll
            for (int fn = 0; fn < 4; ++fn)
#pragma unroll
                for (int fm = 0; fm < 4; ++fm)
                    acc[fn][fm] = __builtin_amdgcn_mfma_f32_16x16x32_bf16(
                        wf[fn], hf[fm], acc[fn][fm], 0, 0, 0);
        }
    }

    // ---- epilogue: relu(acc + b2) -> featL (K-octet-major overlay over Bt)
    __syncthreads();
#pragma unroll
    for (int fn = 0; fn < 4; ++fn) {
        const int fcb = wv * 64 + fn * 16 + quad * 4;   // featcol base
        const float4 b2v = *(const float4*)(B2 + slab * 256 + fcb);
        const int o = fcb >> 3, j = fcb & 7;
#pragma unroll
        for (int fm = 0; fm < 4; ++fm) {
            const int smp = fm * 16 + l15;
            const floatx4 v = acc[fn][fm];
            bf16x4 p;
            p[0] = (__bf16)fmaxf(v[0] + b2v.x, 0.f);
            p[1] = (__bf16)fmaxf(v[1] + b2v.y, 0.f);
            p[2] = (__bf16)fmaxf(v[2] + b2v.z, 0.f);
            p[3] = (__bf16)fmaxf(v[3] + b2v.w, 0.f);
            *(bf16x4*)(featL + (o * 64 + smp) * 8 + j) = p;
        }
    }
    __syncthreads();

    // ---- head MFMA: wave wv -> samples wv*16..+15; WHT direct (L2-hot)
    floatx4 hacc[2] = {};
#pragma unroll
    for (int ks2 = 0; ks2 < 8; ++ks2) {
        const bf16x8 fa = *(const bf16x8*)(featL
                             + ((ks2 * 4 + quad) * 64 + wv * 16 + l15) * 8);
#pragma unroll
        for (int t2 = 0; t2 < 2; ++t2) {
            const int r  = t2 * 16 + l15;
            const int og = slab * 32 + ks2 * 4 + quad;
            const bf16x8 wb = *(const bf16x8*)(WHT + (size_t)og * 256 + r * 8);
            hacc[t2] = __builtin_amdgcn_mfma_f32_16x16x32_bf16(
                fa, wb, hacc[t2], 0, 0, 0);
        }
    }

    // ---- atomic scatter: sample = quad*4+reg; emit selected skill's 4 actions
#pragma unroll
    for (int j = 0; j < 4; ++j) {
        const int smp = wv * 16 + quad * 4 + j;
        const int sk  = SK[i0 + smp];
#pragma unroll
        for (int t2 = 0; t2 < 2; ++t2) {
            const int hc = t2 * 16 + l15;
            const int d  = hc - sk * 4;
            if (d >= 0 && d < 4) {
                float v = hacc[t2][j];
                if (slab == 0) v += BH[hc];
                atomicAdd(&OUT[(i0 + smp) * 4 + d], v);
            }
        }
    }
}

extern "C" void kernel_launch(void* const* d_in, const int* in_sizes, int n_in,
                              void* d_out, int out_size, void* d_ws, size_t ws_size,
                              hipStream_t stream) {
    const float* S  = (const float*)d_in[0];
    const int*   SK = (const int*)d_in[1];
    const float* W1 = (const float*)d_in[2];
    const float* B1 = (const float*)d_in[3];
    const float* W2 = (const float*)d_in[4];
    const float* B2 = (const float*)d_in[5];
    const float* WH = (const float*)d_in[6];
    const float* BH = (const float*)d_in[7];

    char* ws = (char*)d_ws;
    __bf16* W2T = (__bf16*)ws;                          // 2 MiB
    __bf16* WHT = (__bf16*)(ws + 2 * 1024 * 1024);      // 64 KiB

    hipLaunchKernelGGL(prep_all, dim3(544), dim3(256), 0, stream,
                       W2, WH, W2T, WHT, (float*)d_out);
    // grid: 1024 sample-groups x 4 slabs; slab = blockIdx>>10 so co-resident
    // blocks share one W2T slab (L2-friendly)
    hipLaunchKernelGGL(policy_main, dim3(4096), dim3(256), 0, stream,
                       S, SK, W1, B1, W2T, B2, WHT, BH, (float*)d_out);
}